// Round 4
// baseline (489.946 us; speedup 1.0000x reference)
//
#include <hip/hip_runtime.h>

// ---------------------------------------------------------------------------
// AttentionLayer_Spa — MI355X bf16-MFMA pipeline
//   B=4 T=12 N=1024 C=128 D=512 H=8 hd=64 S=60, BT=48
// R4: (1) att launch_bounds (256,4) — LDS 34.8KB fits 4 blocks/CU;
//     (2) adpP precompute — adp rearranged to per-thread contiguous fp32,
//         64 scalar loads -> 16 dwordx4 per thread in att softmax;
//     (3) gemm_bt/g2_kv staging via __builtin_amdgcn_global_load_lds width=16
//         (m97 2-barrier structure; layout already wave-uniform+lane*16).
// ---------------------------------------------------------------------------

#define LOG2E 1.44269504088896f

typedef __attribute__((ext_vector_type(4))) float f32x4;
typedef __attribute__((ext_vector_type(8))) short bf16x8;

#define GLD16(gptr, ldsptr)                                                     \
    __builtin_amdgcn_global_load_lds(                                           \
        (const __attribute__((address_space(1))) unsigned int*)(gptr),          \
        (__attribute__((address_space(3))) unsigned int*)(ldsptr), 16, 0, 0)

__device__ __forceinline__ unsigned short f2bf(float f) {
    union { float f; unsigned u; } v; v.f = f;
    unsigned r = (v.u + 0x7fffu + ((v.u >> 16) & 1u)) >> 16;
    return (unsigned short)r;
}
__device__ __forceinline__ float bf2f(unsigned short h) {
    union { unsigned u; float f; } v; v.u = ((unsigned)h) << 16;
    return v.f;
}

// ---------------------------------------------------------------------------
// K0a: weight/bias conversion (unchanged).
// ---------------------------------------------------------------------------
__global__ void cvt_w(const float* __restrict__ Wq, const float* __restrict__ Wk,
                      const float* __restrict__ Wv, const float* __restrict__ We,
                      const float* __restrict__ Wo, const float* __restrict__ U1,
                      const float* __restrict__ U2,
                      const float* __restrict__ bq, const float* __restrict__ bk,
                      const float* __restrict__ bv, const float* __restrict__ be,
                      unsigned short* __restrict__ Wqe, unsigned short* __restrict__ Wkv,
                      unsigned short* __restrict__ Wob, unsigned short* __restrict__ U1T,
                      unsigned short* __restrict__ U2bT,
                      float* __restrict__ bqe, float* __restrict__ bkv)
{
    int i = blockIdx.x * 256 + threadIdx.x;
    if (i < 524288) {
        int r = i >> 9;
        float v = (r < 512) ? Wq[i] : We[i - 262144];
        Wqe[i] = f2bf(v);
    } else if (i < 1048576) {
        int j = i - 524288; int r = j >> 9;
        float v = (r < 512) ? Wk[j] : Wv[j - 262144];
        Wkv[j] = f2bf(v);
    } else if (i < 1310720) {
        int j = i - 1048576;
        Wob[j] = f2bf(Wo[j]);
    } else if (i < 1314816) {
        int j = i - 1310720; int s = j >> 6, k = j & 63;
        U1T[j] = (s < 60) ? f2bf(U1[k * 60 + s]) : (unsigned short)0;
    } else if (i < 1318912) {
        int j = i - 1314816; int d = j >> 6, s = j & 63;
        U2bT[j] = (s < 60) ? f2bf(U2[s * 64 + d] * 0.5f) : (unsigned short)0;
    } else if (i < 1319936) {
        int j = i - 1318912;
        bqe[j] = (j < 512) ? bq[j] : be[j - 512];
    } else if (i < 1320960) {
        int j = i - 1319936;
        bkv[j] = (j < 512) ? bk[j] : bv[j - 512];
    }
}

// ---------------------------------------------------------------------------
// adp_prep: rearrange adp (1024x128 f32) into att's per-thread order:
//   adpP[((nb*256 + tid)*64) + (i*32 + tn*4 + r)] =
//     adp[(nb*128 + wave*32 + i*16 + quad*4 + r)*128 + tn*16 + l16]
// 131072 elements, grid 512.
// ---------------------------------------------------------------------------
__global__ void adp_prep(const float* __restrict__ adp, float* __restrict__ adpP)
{
    int id = blockIdx.x * 256 + threadIdx.x;   // < 131072
    int nb = id >> 14;
    int tid = (id >> 6) & 255;
    int j = id & 63;
    int wave = tid >> 6, quad = (tid >> 4) & 3, l16 = tid & 15;
    int i = j >> 5, tn = (j >> 2) & 7, r = j & 3;
    int row = nb * 128 + wave * 32 + i * 16 + quad * 4 + r;
    int col = tn * 16 + l16;
    adpP[id] = adp[row * 128 + col];
}

// ---------------------------------------------------------------------------
// K0b: fused x->bf16 + pooled-x->bf16 (unchanged).
// ---------------------------------------------------------------------------
__global__ void cvt_pool(const float* __restrict__ x, unsigned short* __restrict__ xb,
                         unsigned short* __restrict__ xpb)
{
    int i = blockIdx.x * 256 + threadIdx.x;   // < 786432
    int d4 = i & 127;
    int btc = i >> 7;
    int bt = btc >> 7, c = btc & 127;
    long base = ((long)(bt * 1024 + c * 8)) * 128 + d4;
    const float4* src = (const float4*)x + base;
    ushort4* dst = (ushort4*)xb + base;
    float sx = 0.f, sy = 0.f, sz = 0.f, sw = 0.f;
#pragma unroll
    for (int j = 0; j < 8; j++) {
        float4 v = src[(long)j * 128];
        sx += v.x; sy += v.y; sz += v.z; sw += v.w;
        ushort4 o;
        o.x = f2bf(v.x); o.y = f2bf(v.y); o.z = f2bf(v.z); o.w = f2bf(v.w);
        dst[(long)j * 128] = o;
    }
    ushort4 p;
    p.x = f2bf(sx * 0.125f); p.y = f2bf(sy * 0.125f);
    p.z = f2bf(sz * 0.125f); p.w = f2bf(sw * 0.125f);
    ((ushort4*)xpb)[(long)btc * 128 + d4] = p;
}

// ---------------------------------------------------------------------------
// GEMM: C(MxN) = A(MxK) @ W(NxK)^T + bias[N].  global_load_lds staging.
// 128x128 tile, BK=32, 4 waves (2x2 of 64x64), 16x16x32 bf16 MFMA.
// ---------------------------------------------------------------------------
template <int OUTF32>
__global__ __launch_bounds__(256, 3) void gemm_bt(
    const unsigned short* __restrict__ A, const unsigned short* __restrict__ W,
    const float* __restrict__ bias, void* __restrict__ Cout,
    int M, int N, int K)
{
    __shared__ __attribute__((aligned(16))) unsigned short As[128 * 32];
    __shared__ __attribute__((aligned(16))) unsigned short Bs[128 * 32];
    const int tid = threadIdx.x;
    const int wave = tid >> 6, lane = tid & 63;
    const int quad = lane >> 4, l16 = lane & 15;
    const int m0 = blockIdx.x * 128, n0 = blockIdx.y * 128;
    const int wm = (wave & 1) * 64, wn = (wave >> 1) * 64;

    f32x4 acc[4][4];
#pragma unroll
    for (int i = 0; i < 4; i++)
#pragma unroll
        for (int j = 0; j < 4; j++) acc[i][j] = (f32x4){0.f, 0.f, 0.f, 0.f};

    const int c0 = tid, c1 = tid + 256;
    const int r0 = c0 >> 2, kc0 = (c0 & 3) * 8;
    const int r1 = c1 >> 2, kc1 = (c1 & 3) * 8;

    for (int k0 = 0; k0 < K; k0 += 32) {
        __syncthreads();                       // prev-iter LDS reads done
        GLD16(A + (long)(m0 + r0) * K + k0 + kc0, &As[c0 * 8]);
        GLD16(A + (long)(m0 + r1) * K + k0 + kc1, &As[c1 * 8]);
        GLD16(W + (long)(n0 + r0) * K + k0 + kc0, &Bs[c0 * 8]);
        GLD16(W + (long)(n0 + r1) * K + k0 + kc1, &Bs[c1 * 8]);
        __syncthreads();                       // vmcnt drain + barrier
        bf16x8 af[4], bfr[4];
#pragma unroll
        for (int t = 0; t < 4; t++)
            af[t] = *(const bf16x8*)&As[(wm + t * 16 + l16) * 32 + quad * 8];
#pragma unroll
        for (int t = 0; t < 4; t++)
            bfr[t] = *(const bf16x8*)&Bs[(wn + t * 16 + l16) * 32 + quad * 8];
#pragma unroll
        for (int tm = 0; tm < 4; tm++)
#pragma unroll
            for (int tn = 0; tn < 4; tn++)
                acc[tm][tn] = __builtin_amdgcn_mfma_f32_16x16x32_bf16(
                    af[tm], bfr[tn], acc[tm][tn], 0, 0, 0);
    }

#pragma unroll
    for (int tm = 0; tm < 4; tm++)
#pragma unroll
        for (int tn = 0; tn < 4; tn++) {
            int cc = n0 + wn + tn * 16 + l16;
            float bv = bias[cc];
#pragma unroll
            for (int r = 0; r < 4; r++) {
                int rr = m0 + wm + tm * 16 + quad * 4 + r;
                float v = acc[tm][tn][r] + bv;
                if (OUTF32) ((float*)Cout)[(long)rr * N + cc] = v;
                else        ((unsigned short*)Cout)[(long)rr * N + cc] = f2bf(v);
            }
        }
}

// ---------------------------------------------------------------------------
// G2: kv = xp @ Wkv^T + bkv.  K half -> kvK row-major; V half -> vT transposed.
// ---------------------------------------------------------------------------
__global__ __launch_bounds__(256, 3) void g2_kv(
    const unsigned short* __restrict__ A, const unsigned short* __restrict__ W,
    const float* __restrict__ bias, unsigned short* __restrict__ kvK,
    unsigned short* __restrict__ vT)
{
    const int K = 512;
    __shared__ __attribute__((aligned(16))) unsigned short As[128 * 32];
    __shared__ __attribute__((aligned(16))) unsigned short Bs[128 * 32];
    const int tid = threadIdx.x;
    const int wave = tid >> 6, lane = tid & 63;
    const int quad = lane >> 4, l16 = lane & 15;
    const int m0 = blockIdx.x * 128, n0 = blockIdx.y * 128;
    const int wm = (wave & 1) * 64, wn = (wave >> 1) * 64;

    f32x4 acc[4][4];
#pragma unroll
    for (int i = 0; i < 4; i++)
#pragma unroll
        for (int j = 0; j < 4; j++) acc[i][j] = (f32x4){0.f, 0.f, 0.f, 0.f};

    const int c0 = tid, c1 = tid + 256;
    const int r0 = c0 >> 2, kc0 = (c0 & 3) * 8;
    const int r1 = c1 >> 2, kc1 = (c1 & 3) * 8;

    for (int k0 = 0; k0 < K; k0 += 32) {
        __syncthreads();
        GLD16(A + (long)(m0 + r0) * K + k0 + kc0, &As[c0 * 8]);
        GLD16(A + (long)(m0 + r1) * K + k0 + kc1, &As[c1 * 8]);
        GLD16(W + (long)(n0 + r0) * K + k0 + kc0, &Bs[c0 * 8]);
        GLD16(W + (long)(n0 + r1) * K + k0 + kc1, &Bs[c1 * 8]);
        __syncthreads();
        bf16x8 af[4], bfr[4];
#pragma unroll
        for (int t = 0; t < 4; t++)
            af[t] = *(const bf16x8*)&As[(wm + t * 16 + l16) * 32 + quad * 8];
#pragma unroll
        for (int t = 0; t < 4; t++)
            bfr[t] = *(const bf16x8*)&Bs[(wn + t * 16 + l16) * 32 + quad * 8];
#pragma unroll
        for (int tm = 0; tm < 4; tm++)
#pragma unroll
            for (int tn = 0; tn < 4; tn++)
                acc[tm][tn] = __builtin_amdgcn_mfma_f32_16x16x32_bf16(
                    af[tm], bfr[tn], acc[tm][tn], 0, 0, 0);
    }

#pragma unroll
    for (int tm = 0; tm < 4; tm++)
#pragma unroll
        for (int tn = 0; tn < 4; tn++) {
            int cc = n0 + wn + tn * 16 + l16;
            float bv = bias[cc];
            int rrb = m0 + wm + tm * 16 + quad * 4;
            if (cc < 512) {
#pragma unroll
                for (int r = 0; r < 4; r++)
                    kvK[(long)(rrb + r) * 512 + cc] = f2bf(acc[tm][tn][r] + bv);
            } else {
                int hh = (cc - 512) >> 6, dd = (cc - 512) & 63;
                int btv = rrb >> 7, cv = rrb & 127;
                ushort4 o;
                o.x = f2bf(acc[tm][tn][0] + bv);
                o.y = f2bf(acc[tm][tn][1] + bv);
                o.z = f2bf(acc[tm][tn][2] + bv);
                o.w = f2bf(acc[tm][tn][3] + bv);
                *(ushort4*)(vT + ((long)(btv * 8 + hh) * 64 + dd) * 128 + cv) = o;
            }
        }
}

// ---------------------------------------------------------------------------
// EZ: Z = ev @ U1 per (bt,h,nb). (register staging kept: padded LDS)
// ---------------------------------------------------------------------------
__global__ __launch_bounds__(256, 2) void ez_kernel(
    const unsigned short* __restrict__ qev, const unsigned short* __restrict__ U1T,
    unsigned short* __restrict__ Z)
{
    __shared__ __attribute__((aligned(16))) unsigned short evs[128 * 72];
    __shared__ __attribute__((aligned(16))) unsigned short u1s[64 * 72];
    int tid = threadIdx.x, bx = blockIdx.x;
    int bt = bx >> 6, h = (bx >> 3) & 7, nb = bx & 7;
    int wave = tid >> 6, lane = tid & 63, quad = lane >> 4, l16 = lane & 15;

#pragma unroll
    for (int i = 0; i < 4; i++) {
        int c = tid + i * 256; int row = c >> 3, kc = (c & 7) * 8;
        *(int4*)&evs[row * 72 + kc] =
            *(const int4*)(qev + ((long)(bt * 1024 + nb * 128 + row)) * 1024 + 512 + h * 64 + kc);
    }
#pragma unroll
    for (int i = 0; i < 2; i++) {
        int c = tid + i * 256; int row = c >> 3, kc = (c & 7) * 8;
        *(int4*)&u1s[row * 72 + kc] = *(const int4*)(U1T + row * 64 + kc);
    }
    __syncthreads();

    f32x4 acc[2][4];
#pragma unroll
    for (int i = 0; i < 2; i++)
#pragma unroll
        for (int t = 0; t < 4; t++) acc[i][t] = (f32x4){0.f, 0.f, 0.f, 0.f};

#pragma unroll
    for (int kt = 0; kt < 2; kt++) {
        bf16x8 a[2], b[4];
#pragma unroll
        for (int i = 0; i < 2; i++)
            a[i] = *(const bf16x8*)&evs[((wave * 2 + i) * 16 + l16) * 72 + kt * 32 + quad * 8];
#pragma unroll
        for (int t = 0; t < 4; t++)
            b[t] = *(const bf16x8*)&u1s[(t * 16 + l16) * 72 + kt * 32 + quad * 8];
#pragma unroll
        for (int i = 0; i < 2; i++)
#pragma unroll
            for (int t = 0; t < 4; t++)
                acc[i][t] = __builtin_amdgcn_mfma_f32_16x16x32_bf16(a[i], b[t], acc[i][t], 0, 0, 0);
    }

    long zb = (long)(bt * 8 + h) * 1024 + nb * 128;
#pragma unroll
    for (int i = 0; i < 2; i++)
#pragma unroll
        for (int t = 0; t < 4; t++) {
            int s = t * 16 + l16;
            if (s < 60) {
#pragma unroll
                for (int r = 0; r < 4; r++) {
                    int rr = (wave * 2 + i) * 16 + quad * 4 + r;
                    Z[(zb + rr) * 60 + s] = f2bf(acc[i][t][r]);
                }
            }
        }
}

// ---------------------------------------------------------------------------
// ES: per (bt,h): column softmax stats over n for s<60.
// ---------------------------------------------------------------------------
__global__ __launch_bounds__(256, 2) void es_kernel(
    const unsigned short* __restrict__ Z, float* __restrict__ mS, float* __restrict__ lSinv)
{
    __shared__ float ms[4][64];
    __shared__ float ls[4][64];
    int tid = threadIdx.x;
    int s = tid & 63, g = tid >> 6;
    long zb = (long)blockIdx.x * 1024 * 60;
    float m = -1e30f, l = 0.f;
    if (s < 60) {
        for (int r = 0; r < 256; r++) {
            float z = bf2f(Z[zb + (long)(g * 256 + r) * 60 + s]);
            float nm = fmaxf(m, z);
            l = l * exp2f((m - nm) * LOG2E) + exp2f((z - nm) * LOG2E);
            m = nm;
        }
    }
    ms[g][s] = m; ls[g][s] = l;
    __syncthreads();
    if (tid < 60) {
        float M = fmaxf(fmaxf(ms[0][tid], ms[1][tid]), fmaxf(ms[2][tid], ms[3][tid]));
        float L = 0.f;
#pragma unroll
        for (int gg = 0; gg < 4; gg++) L += ls[gg][tid] * exp2f((ms[gg][tid] - M) * LOG2E);
        mS[blockIdx.x * 60 + tid] = M;
        lSinv[blockIdx.x * 60 + tid] = 1.0f / L;
    }
}

// ---------------------------------------------------------------------------
// ATT v3: per (bt,h,nb): no barriers, adpP vector loads, 4 blocks/CU.
// ---------------------------------------------------------------------------
__global__ __launch_bounds__(256, 4) void att_kernel(
    const unsigned short* __restrict__ qev, const unsigned short* __restrict__ kvK,
    const unsigned short* __restrict__ vT, const unsigned short* __restrict__ Z,
    const float* __restrict__ mS, const float* __restrict__ lI,
    const float* __restrict__ adpP, const unsigned short* __restrict__ U2bT,
    unsigned short* __restrict__ attn_out)
{
    __shared__ __attribute__((aligned(16))) unsigned short Ps[128 * 136];

    int tid = threadIdx.x, bx = blockIdx.x;
    int bt = bx >> 6, h = (bx >> 3) & 7, nb = bx & 7;
    int wave = tid >> 6, lane = tid & 63, quad = lane >> 4, l16 = lane & 15;
    int n0 = nb * 128;
    const int g = bt * 8 + h;
    const long qrow0 = (long)bt * 1024 + n0;

    // --- score: S = q @ k^T ---
    f32x4 sc[2][8];
#pragma unroll
    for (int i = 0; i < 2; i++)
#pragma unroll
        for (int t = 0; t < 8; t++) sc[i][t] = (f32x4){0.f, 0.f, 0.f, 0.f};

#pragma unroll
    for (int kt = 0; kt < 2; kt++) {
        bf16x8 a[2];
#pragma unroll
        for (int i = 0; i < 2; i++)
            a[i] = *(const bf16x8*)(qev + (qrow0 + (wave * 2 + i) * 16 + l16) * 1024
                                    + h * 64 + kt * 32 + quad * 8);
#pragma unroll
        for (int tn = 0; tn < 8; tn++) {
            bf16x8 b = *(const bf16x8*)(kvK + (long)(bt * 128 + tn * 16 + l16) * 512
                                        + h * 64 + kt * 32 + quad * 8);
#pragma unroll
            for (int i = 0; i < 2; i++)
                sc[i][tn] = __builtin_amdgcn_mfma_f32_16x16x32_bf16(a[i], b, sc[i][tn], 0, 0, 0);
        }
    }

    // --- softmax over 128 cols; adp via adpP (contiguous per thread) ---
    const float* ap = adpP + ((long)nb * 256 + tid) * 64;
#pragma unroll
    for (int i = 0; i < 2; i++) {
        f32x4 av[8];
#pragma unroll
        for (int t = 0; t < 8; t++) av[t] = *(const f32x4*)(ap + i * 32 + t * 4);
#pragma unroll
        for (int tn = 0; tn < 8; tn++)
#pragma unroll
            for (int r = 0; r < 4; r++)
                sc[i][tn][r] = sc[i][tn][r] * 0.125f + av[tn][r];
        float rmax[4], rsum[4];
#pragma unroll
        for (int r = 0; r < 4; r++) {
            float m = sc[i][0][r];
#pragma unroll
            for (int tn = 1; tn < 8; tn++) m = fmaxf(m, sc[i][tn][r]);
#pragma unroll
            for (int d = 1; d < 16; d <<= 1) m = fmaxf(m, __shfl_xor(m, d, 64));
            rmax[r] = m; rsum[r] = 0.f;
        }
#pragma unroll
        for (int tn = 0; tn < 8; tn++)
#pragma unroll
            for (int r = 0; r < 4; r++) {
                float p = exp2f((sc[i][tn][r] - rmax[r]) * LOG2E);
                sc[i][tn][r] = p; rsum[r] += p;
            }
#pragma unroll
        for (int r = 0; r < 4; r++) {
#pragma unroll
            for (int d = 1; d < 16; d <<= 1) rsum[r] += __shfl_xor(rsum[r], d, 64);
            rsum[r] = 1.0f / rsum[r];
        }
#pragma unroll
        for (int tn = 0; tn < 8; tn++)
#pragma unroll
            for (int r = 0; r < 4; r++) {
                int rr = (wave * 2 + i) * 16 + quad * 4 + r;
                Ps[rr * 136 + tn * 16 + l16] = f2bf(sc[i][tn][r] * rsum[r]);
            }
    }
    // no barrier: wave-private Ps rows.

    // --- out = P @ vh (K=128) ---
    f32x4 oc[2][4];
#pragma unroll
    for (int i = 0; i < 2; i++)
#pragma unroll
        for (int t = 0; t < 4; t++) oc[i][t] = (f32x4){0.f, 0.f, 0.f, 0.f};

#pragma unroll
    for (int kt = 0; kt < 4; kt++) {
        bf16x8 a[2];
#pragma unroll
        for (int i = 0; i < 2; i++)
            a[i] = *(const bf16x8*)&Ps[((wave * 2 + i) * 16 + l16) * 136 + kt * 32 + quad * 8];
#pragma unroll
        for (int tn = 0; tn < 4; tn++) {
            bf16x8 b = *(const bf16x8*)(vT + ((long)g * 64 + tn * 16 + l16) * 128
                                        + kt * 32 + quad * 8);
#pragma unroll
            for (int i = 0; i < 2; i++)
                oc[i][tn] = __builtin_amdgcn_mfma_f32_16x16x32_bf16(a[i], b, oc[i][tn], 0, 0, 0);
        }
    }

    // --- += exa @ U2b (K=64), exa built in registers ---
#pragma unroll
    for (int kt = 0; kt < 2; kt++) {
        int sb = kt * 32 + quad * 8;
        float4 ma = *(const float4*)(mS + (long)g * 60 + sb);
        float4 mb2 = *(const float4*)(mS + (long)g * 60 + sb + 4);
        float4 la = *(const float4*)(lI + (long)g * 60 + sb);
        float4 lb2 = *(const float4*)(lI + (long)g * 60 + sb + 4);
        float mv[8] = {ma.x, ma.y, ma.z, ma.w, mb2.x, mb2.y, mb2.z, mb2.w};
        float lv[8] = {la.x, la.y, la.z, la.w, lb2.x, lb2.y, lb2.z, lb2.w};
        bf16x8 ea[2];
#pragma unroll
        for (int i = 0; i < 2; i++) {
            int row = (wave * 2 + i) * 16 + l16;
            const unsigned short* zp = Z + ((long)g * 1024 + n0 + row) * 60 + sb;
            uint2 z0 = *(const uint2*)zp;
            uint2 z1 = *(const uint2*)(zp + 4);
            unsigned zz[4] = {z0.x, z0.y, z1.x, z1.y};
            unsigned short es_[8];
#pragma unroll
            for (int j = 0; j < 8; j++) {
                unsigned short zh = (unsigned short)((zz[j >> 1] >> ((j & 1) * 16)) & 0xffff);
                float e = (sb + j < 60)
                    ? exp2f((bf2f(zh) - mv[j]) * LOG2E) * lv[j] : 0.f;
                es_[j] = f2bf(e);
            }
            ea[i] = *(bf16x8*)es_;
        }
#pragma unroll
        for (int tn = 0; tn < 4; tn++) {
            bf16x8 b = *(const bf16x8*)(U2bT + (tn * 16 + l16) * 64 + sb);
#pragma unroll
            for (int i = 0; i < 2; i++)
                oc[i][tn] = __builtin_amdgcn_mfma_f32_16x16x32_bf16(ea[i], b, oc[i][tn], 0, 0, 0);
        }
    }

    // --- epilogue: + ev, write merged-head attn_out (bf16) ---
#pragma unroll
    for (int i = 0; i < 2; i++)
#pragma unroll
        for (int tn = 0; tn < 4; tn++)
#pragma unroll
            for (int r = 0; r < 4; r++) {
                int rr = (wave * 2 + i) * 16 + quad * 4 + r;
                int cc = tn * 16 + l16;
                float ev = bf2f(qev[(qrow0 + rr) * 1024 + 512 + h * 64 + cc]);
                attn_out[(qrow0 + rr) * 512 + h * 64 + cc] = f2bf(oc[i][tn][r] + ev);
            }
}

// ---------------------------------------------------------------------------
// launch
// ---------------------------------------------------------------------------
extern "C" void kernel_launch(void* const* d_in, const int* in_sizes, int n_in,
                              void* d_out, int out_size, void* d_ws, size_t ws_size,
                              hipStream_t stream)
{
    const float* x   = (const float*)d_in[0];
    const float* Wq  = (const float*)d_in[1];
    const float* bq  = (const float*)d_in[2];
    const float* Wk  = (const float*)d_in[3];
    const float* bk  = (const float*)d_in[4];
    const float* Wv  = (const float*)d_in[5];
    const float* bv  = (const float*)d_in[6];
    const float* We  = (const float*)d_in[7];
    const float* be  = (const float*)d_in[8];
    const float* Wo  = (const float*)d_in[9];
    const float* bo  = (const float*)d_in[10];
    const float* adp = (const float*)d_in[11];
    const float* U1  = (const float*)d_in[12];
    const float* U2  = (const float*)d_in[13];

    char* ws = (char*)d_ws;
    unsigned short* xb   = (unsigned short*)(ws + 0);          // 50,331,648 B
    unsigned short* aout = xb;                                 // alias: xb dead after G1
    unsigned short* xpb  = (unsigned short*)(ws + 50331648);   //  6,291,456
    unsigned short* qev  = (unsigned short*)(ws + 56623104);   // 100,663,296
    unsigned short* kvK  = (unsigned short*)(ws + 157286400);  //  6,291,456
    unsigned short* vT   = (unsigned short*)(ws + 163577856);  //  6,291,456
    unsigned short* Zb   = (unsigned short*)(ws + 169869312);  // 47,185,920
    unsigned short* Wqe  = (unsigned short*)(ws + 217055232);  //  1,048,576
    unsigned short* Wkv  = (unsigned short*)(ws + 218103808);  //  1,048,576
    unsigned short* Wob  = (unsigned short*)(ws + 219152384);  //    524,288
    unsigned short* U1T  = (unsigned short*)(ws + 219676672);  //      8,192
    unsigned short* U2bT = (unsigned short*)(ws + 219684864);  //      8,192
    float*          mSb  = (float*)(ws + 219693056);           //     92,160
    float*          lIb  = (float*)(ws + 219785216);           //     92,160
    float*          bqe  = (float*)(ws + 219877376);           //      4,096
    float*          bkv  = (float*)(ws + 219881472);           //      4,096
    float*          adpP = (float*)(ws + 219885568);           //    524,288
    // total: 220,409,856 B

    cvt_w<<<5160, 256, 0, stream>>>(Wq, Wk, Wv, We, Wo, U1, U2, bq, bk, bv, be,
                                    Wqe, Wkv, Wob, U1T, U2bT, bqe, bkv);
    adp_prep<<<512, 256, 0, stream>>>(adp, adpP);
    cvt_pool<<<3072, 256, 0, stream>>>(x, xb, xpb);

    gemm_bt<0><<<dim3(384, 8), 256, 0, stream>>>(xb,  Wqe, bqe, (void*)qev, 49152, 1024, 512);
    g2_kv<<<dim3(48, 8), 256, 0, stream>>>(xpb, Wkv, bkv, kvK, vT);

    ez_kernel<<<3072, 256, 0, stream>>>(qev, U1T, Zb);
    es_kernel<<<384, 256, 0, stream>>>(Zb, mSb, lIb);
    att_kernel<<<3072, 256, 0, stream>>>(qev, kvK, vT, Zb, mSb, lIb, adpP, U2bT, aout);

    gemm_bt<1><<<dim3(384, 4), 256, 0, stream>>>(aout, Wob, bo, d_out, 49152, 512, 512);
}